// Round 16
// baseline (221.675 us; speedup 1.0000x reference)
//
#include <hip/hip_runtime.h>
#include <math.h>

#define BN_EPS 1e-5f

typedef unsigned short u16;
typedef unsigned int u32;
typedef unsigned char u8;
typedef __attribute__((ext_vector_type(8))) short bf16x8;
typedef __attribute__((ext_vector_type(4))) float f32x4;
typedef __attribute__((ext_vector_type(2))) float f32x2;

__device__ __forceinline__ u16 f2bf(float f) {
  u32 u = __float_as_uint(f);
  u32 r = (u + 0x7fffu + ((u >> 16) & 1u)) >> 16;   // RNE
  return (u16)r;
}
__device__ __forceinline__ u32 packbf2(float x, float y) {
  return (u32)f2bf(x) | ((u32)f2bf(y) << 16);
}
__device__ __forceinline__ float lo_bf(u32 p) { return __uint_as_float(p << 16); }
__device__ __forceinline__ float hi_bf(u32 p) { return __uint_as_float(p & 0xffff0000u); }

__device__ __forceinline__ void unpack8(uint4 p, float* f) {
  f[0] = lo_bf(p.x); f[1] = hi_bf(p.x);
  f[2] = lo_bf(p.y); f[3] = hi_bf(p.y);
  f[4] = lo_bf(p.z); f[5] = hi_bf(p.z);
  f[6] = lo_bf(p.w); f[7] = hi_bf(p.w);
}

// fp8 e4m3 x4 unpack, packed 2-at-a-time (v_cvt_pk_f32_fp8)
__device__ __forceinline__ void unpack_fp8x4(u32 p, float* f) {
  f32x2 lo = __builtin_amdgcn_cvt_pk_f32_fp8((int)p, false);
  f32x2 hi = __builtin_amdgcn_cvt_pk_f32_fp8((int)p, true);
  f[0] = lo.x; f[1] = lo.y; f[2] = hi.x; f[3] = hi.y;
}
__device__ __forceinline__ u8 f2fp8(float o) {
  u32 pk = __builtin_amdgcn_cvt_pk_fp8_f32(o, o, 0, false);
  return (u8)(pk & 0xffu);
}

// ---------------- workspace clear ----------------
__global__ __launch_bounds__(256) void clear_k(int* __restrict__ p, int n) {
  int i = blockIdx.x * 256 + threadIdx.x;
  if (i < n) p[i] = 0;
}

// ---------------- CSR build (8-way replicated counters) ----------------
// replica r = e & 7; pintra[e] = position within (replica, dst) bucket
__global__ __launch_bounds__(256) void count_pos_k(const int* __restrict__ dst,
                                                   int* __restrict__ cntR,
                                                   int* __restrict__ pintra,
                                                   int N, int E) {
  int e = blockIdx.x * 256 + threadIdx.x;
  if (e >= E) return;
  int d = dst[e];
  int r = e & 7;
  int p = atomicAdd(&cntR[(size_t)r * N + d], 1);
  pintra[e] = p;
}

// per-node: total over 8 replicas -> cnt, dinv; overwrite replicas with excl offsets
__global__ __launch_bounds__(256) void rowsum_k(int* __restrict__ cntR,
                                                int* __restrict__ cnt,
                                                float* __restrict__ dinv, int N) {
  int i = blockIdx.x * 256 + threadIdx.x;
  if (i >= N) return;
  int c[8];
  #pragma unroll
  for (int r = 0; r < 8; ++r) c[r] = cntR[(size_t)r * N + i];
  int run = 0;
  #pragma unroll
  for (int r = 0; r < 8; ++r) {
    int v = c[r];
    cntR[(size_t)r * N + i] = run;
    run += v;
  }
  cnt[i] = run;
  dinv[i] = rsqrtf((float)(run + 1));   // deg = in-degree + self-loop
}

__global__ __launch_bounds__(256) void blocksum_k(const int* __restrict__ cnt,
                                                  int* __restrict__ bsum, int n) {
  __shared__ int red[256];
  int tid = threadIdx.x;
  int i = blockIdx.x * 256 + tid;
  int v = (i < n) ? cnt[i] : 0;
  red[tid] = v;
  __syncthreads();
  for (int o = 128; o > 0; o >>= 1) {
    if (tid < o) red[tid] += red[tid + o];
    __syncthreads();
  }
  if (tid == 0) bsum[blockIdx.x] = red[0];
}

__global__ __launch_bounds__(1024) void scan_bsum_k(int* __restrict__ bsum, int nb) {
  __shared__ int part[1024];
  int tid = threadIdx.x;
  int v = (tid < nb) ? bsum[tid] : 0;
  part[tid] = v;
  __syncthreads();
  for (int o = 1; o < 1024; o <<= 1) {
    int t = (tid >= o) ? part[tid - o] : 0;
    __syncthreads();
    part[tid] += t;
    __syncthreads();
  }
  if (tid < nb) bsum[tid] = part[tid] - v;   // exclusive
}

__global__ __launch_bounds__(256) void scan_final_k(const int* __restrict__ cnt,
                                                    const int* __restrict__ bsum,
                                                    int* __restrict__ rowptr, int n) {
  __shared__ int part[256];
  int tid = threadIdx.x;
  int i = blockIdx.x * 256 + tid;
  int v = (i < n) ? cnt[i] : 0;
  part[tid] = v;
  __syncthreads();
  for (int o = 1; o < 256; o <<= 1) {
    int t = (tid >= o) ? part[tid - o] : 0;
    __syncthreads();
    part[tid] += t;
    __syncthreads();
  }
  if (i < n) {
    int excl = part[tid] - v + bsum[blockIdx.x];
    rowptr[i] = excl;
    if (i == n - 1) rowptr[n] = excl + v;
  }
}

// scatter 4B src per edge; slot = rowptr[d] + repoff[r][d] + pintra[e]
__global__ __launch_bounds__(256) void fill_csr_k(const int* __restrict__ src,
                                                  const int* __restrict__ dst,
                                                  const int* __restrict__ rowptr,
                                                  const int* __restrict__ cntR,
                                                  const int* __restrict__ pintra,
                                                  int* __restrict__ csrS,
                                                  int N, int T, int E) {
  int t = blockIdx.x * 256 + threadIdx.x;
  if (t >= T) return;
  #pragma unroll
  for (int u = 0; u < 4; ++u) {
    int e = t + u * T;
    if (e < E) {
      int d = dst[e];
      int r = e & 7;
      int p = rowptr[d] + cntR[(size_t)r * N + d] + pintra[e];
      csrS[p] = src[e];
    }
  }
}

// ---- prep: weights fp32->transposed bf16 (blocks 0..255) + BN fold (block 256) ----
__global__ __launch_bounds__(256) void prep_k(const float* __restrict__ W1,
    const float* __restrict__ W2, const float* __restrict__ epW1,
    const float* __restrict__ b1, const float* __restrict__ g1,
    const float* __restrict__ be1, const float* __restrict__ m1,
    const float* __restrict__ v1,
    const float* __restrict__ b2, const float* __restrict__ g2,
    const float* __restrict__ be2, const float* __restrict__ m2,
    const float* __restrict__ v2,
    u16* __restrict__ wout, float* __restrict__ bnout) {
  if (blockIdx.x < 256) {
    int t = blockIdx.x * 256 + threadIdx.x;   // 4 * 16384
    int m = t >> 14, r = t & 16383;
    int n = r >> 7, k = r & 127;
    const float* src = (m == 0) ? W1 : (m == 1) ? W2 : epW1 + (size_t)(m - 2) * 16384;
    wout[t] = f2bf(src[k * 128 + n]);
  } else {
    int t = threadIdx.x;
    int layer = t >> 7, c = t & 127;
    const float* bb = layer ? b2 : b1;
    const float* gg = layer ? g2 : g1;
    const float* ee = layer ? be2 : be1;
    const float* mm = layer ? m2 : m1;
    const float* vv = layer ? v2 : v1;
    float alpha = gg[c] * rsqrtf(vv[c] + BN_EPS);
    float beta = (bb[c] - mm[c]) * alpha + ee[c];
    bnout[layer * 256 + c] = alpha;
    bnout[layer * 256 + 128 + c] = beta;
  }
}

// ---- MFMA GEMM: Y[M,128] = (X[M,128] @ W) (* dinv[row]); out bf16 or fp8 ----
template<bool BF16IN, bool SCALE, bool FP8OUT>
__global__ __launch_bounds__(256) void gemm_mfma_k(const void* __restrict__ Xv,
    const u16* __restrict__ Wt, const float* __restrict__ dinv,
    void* __restrict__ Yv, int M) {
  __shared__ u16 Xs[64][136];
  __shared__ u16 Ws[128][136];
  int tid = threadIdx.x;
  int row0 = blockIdx.x * 64;
  for (int i = tid; i < 2048; i += 256) {
    int n = i >> 4, c8 = i & 15;
    uint4 v = ((const uint4*)Wt)[i];
    *(uint4*)&Ws[n][c8 * 8] = v;
  }
  for (int i = tid; i < 1024; i += 256) {
    int r = i >> 4, c8 = i & 15;
    int gr = row0 + r;
    uint4 v = make_uint4(0u, 0u, 0u, 0u);
    if (gr < M) {
      if (BF16IN) {
        v = ((const uint4*)Xv)[(size_t)gr * 16 + c8];
      } else {
        const float* Xf = (const float*)Xv;
        float4 f0 = ((const float4*)Xf)[(size_t)gr * 32 + c8 * 2];
        float4 f1 = ((const float4*)Xf)[(size_t)gr * 32 + c8 * 2 + 1];
        v.x = packbf2(f0.x, f0.y); v.y = packbf2(f0.z, f0.w);
        v.z = packbf2(f1.x, f1.y); v.w = packbf2(f1.z, f1.w);
      }
    }
    *(uint4*)&Xs[r][c8 * 8] = v;
  }
  __syncthreads();
  int w = tid >> 6, l = tid & 63;
  int lr = l & 15, kq = l >> 4;
  bf16x8 a[4];
  #pragma unroll
  for (int kk = 0; kk < 4; ++kk)
    a[kk] = *(const bf16x8*)&Xs[w * 16 + lr][kk * 32 + kq * 8];
  float sc[4];
  #pragma unroll
  for (int r = 0; r < 4; ++r) {
    int grow = row0 + w * 16 + kq * 4 + r;
    sc[r] = (SCALE && grow < M) ? dinv[grow] : 1.f;
  }
  #pragma unroll
  for (int ct = 0; ct < 8; ++ct) {
    f32x4 c = {0.f, 0.f, 0.f, 0.f};
    #pragma unroll
    for (int kk = 0; kk < 4; ++kk) {
      bf16x8 b = *(const bf16x8*)&Ws[ct * 16 + lr][kk * 32 + kq * 8];
      c = __builtin_amdgcn_mfma_f32_16x16x32_bf16(a[kk], b, c, 0, 0, 0);
    }
    int n = ct * 16 + lr;
    #pragma unroll
    for (int r = 0; r < 4; ++r) {
      int grow = row0 + w * 16 + kq * 4 + r;
      if (grow < M) {
        float o = c[r];
        if (SCALE) o *= sc[r];
        if (FP8OUT) {
          ((u8*)Yv)[(size_t)grow * 128 + n] = f2fp8(o);
        } else {
          ((u16*)Yv)[(size_t)grow * 128 + n] = f2bf(o);
        }
      }
    }
  }
}

// ---- fused double GEMM (edge predictor): A out fp8 e4m3 (+bias), B out bf16 ----
__global__ __launch_bounds__(256) void gemm_mfma2_k(const u16* __restrict__ X,
    const u16* __restrict__ WtA, const u16* __restrict__ WtB,
    const float* __restrict__ bias, u8* __restrict__ YA8, u16* __restrict__ YB, int M) {
  __shared__ u16 Xs[64][136];
  __shared__ u16 Ws[128][136];
  int tid = threadIdx.x;
  int row0 = blockIdx.x * 64;
  for (int i = tid; i < 1024; i += 256) {
    int r = i >> 4, c8 = i & 15;
    int gr = row0 + r;
    uint4 v = make_uint4(0u, 0u, 0u, 0u);
    if (gr < M) v = ((const uint4*)X)[(size_t)gr * 16 + c8];
    *(uint4*)&Xs[r][c8 * 8] = v;
  }
  __syncthreads();
  int w = tid >> 6, l = tid & 63;
  int lr = l & 15, kq = l >> 4;
  bf16x8 a[4];
  #pragma unroll
  for (int kk = 0; kk < 4; ++kk)
    a[kk] = *(const bf16x8*)&Xs[w * 16 + lr][kk * 32 + kq * 8];

  for (int m = 0; m < 2; ++m) {
    const u16* Wt = m ? WtB : WtA;
    __syncthreads();
    for (int i = tid; i < 2048; i += 256) {
      int n = i >> 4, c8 = i & 15;
      uint4 v = ((const uint4*)Wt)[i];
      *(uint4*)&Ws[n][c8 * 8] = v;
    }
    __syncthreads();
    #pragma unroll
    for (int ct = 0; ct < 8; ++ct) {
      f32x4 c = {0.f, 0.f, 0.f, 0.f};
      #pragma unroll
      for (int kk = 0; kk < 4; ++kk) {
        bf16x8 b = *(const bf16x8*)&Ws[ct * 16 + lr][kk * 32 + kq * 8];
        c = __builtin_amdgcn_mfma_f32_16x16x32_bf16(a[kk], b, c, 0, 0, 0);
      }
      int n = ct * 16 + lr;
      if (m == 0) {
        float bv = bias[n];
        #pragma unroll
        for (int r = 0; r < 4; ++r) {
          int grow = row0 + w * 16 + kq * 4 + r;
          if (grow < M) YA8[(size_t)grow * 128 + n] = f2fp8(c[r] + bv);
        }
      } else {
        #pragma unroll
        for (int r = 0; r < 4; ++r) {
          int grow = row0 + w * 16 + kq * 4 + r;
          if (grow < M) YB[(size_t)grow * 128 + n] = f2bf(c[r]);
        }
      }
    }
  }
}

// --- agg: 16 lanes/node (4 nodes/wave); masked 8-deep gather; folded BN ---
__global__ __launch_bounds__(256) void agg_bn_relu_k(const u8* __restrict__ XW8,
    const int* __restrict__ rowptr, const int* __restrict__ csrS,
    const float* __restrict__ dinv, const float* __restrict__ ab,
    uint4* __restrict__ H4, int n) {
  int node = (blockIdx.x * 256 + threadIdx.x) >> 4;
  if (node >= n) return;
  int l16 = threadIdx.x & 15;
  int beg = rowptr[node], end = rowptr[node + 1];
  const uint2* X2 = (const uint2*)XW8;   // row = 16 uint2 (128B)
  float ac[8];
  #pragma unroll
  for (int j = 0; j < 8; ++j) ac[j] = 0.f;
  float f[8];
  for (int i = beg; i < end; i += 8) {
    int s[8];
    bool h[8];
    #pragma unroll
    for (int u = 0; u < 8; ++u) {
      int idx = i + u;
      h[u] = idx < end;
      s[u] = h[u] ? csrS[idx] : csrS[i];
    }
    uint2 p[8];
    #pragma unroll
    for (int u = 0; u < 8; ++u) p[u] = X2[(size_t)s[u] * 16 + l16];
    #pragma unroll
    for (int u = 0; u < 8; ++u) {
      if (h[u]) {
        unpack_fp8x4(p[u].x, f); unpack_fp8x4(p[u].y, f + 4);
        #pragma unroll
        for (int j = 0; j < 8; ++j) ac[j] += f[j];
      }
    }
  }
  {
    uint2 p = X2[(size_t)node * 16 + l16];
    unpack_fp8x4(p.x, f); unpack_fp8x4(p.y, f + 4);
    #pragma unroll
    for (int j = 0; j < 8; ++j) ac[j] += f[j];
  }
  float dn = dinv[node];
  int c = l16 * 8;
  float4 a0 = *(const float4*)&ab[c];
  float4 a1 = *(const float4*)&ab[c + 4];
  float4 t0 = *(const float4*)&ab[128 + c];
  float4 t1 = *(const float4*)&ab[128 + c + 4];
  float al[8] = {a0.x, a0.y, a0.z, a0.w, a1.x, a1.y, a1.z, a1.w};
  float bt[8] = {t0.x, t0.y, t0.z, t0.w, t1.x, t1.y, t1.z, t1.w};
  u32 out[4];
  #pragma unroll
  for (int j2 = 0; j2 < 4; ++j2) {
    float o0 = fmaxf(fmaf(ac[2*j2]     * dn, al[2*j2],     bt[2*j2]),     0.f);
    float o1 = fmaxf(fmaf(ac[2*j2 + 1] * dn, al[2*j2 + 1], bt[2*j2 + 1]), 0.f);
    out[j2] = packbf2(o0, o1);
  }
  H4[(size_t)node * 16 + l16] = make_uint4(out[0], out[1], out[2], out[3]);
}

// --- edge pass: node-major; B[d] bf16 in regs; gather A[s] fp8; 4 loads in flight ---
__global__ __launch_bounds__(256) void edge_pass_k(const u8* __restrict__ A8,
    const uint4* __restrict__ B4, const int* __restrict__ rowptr,
    const int* __restrict__ csrS, const float* __restrict__ w2,
    float* __restrict__ pout, int n) {
  int node = (blockIdx.x * 256 + threadIdx.x) >> 6;
  if (node >= n) return;
  int lane = threadIdx.x & 63;
  int sub = lane >> 4, l16 = lane & 15;
  int beg = rowptr[node], end = rowptr[node + 1];
  if (beg >= end) return;
  float bvals[8];
  unpack8(B4[(size_t)node * 16 + l16], bvals);
  int c = l16 * 8;
  float4 w0 = *(const float4*)&w2[c];
  float4 w1 = *(const float4*)&w2[c + 4];
  float wv[8] = {w0.x, w0.y, w0.z, w0.w, w1.x, w1.y, w1.z, w1.w};
  const uint2* A2 = (const uint2*)A8;
  for (int i = beg + sub; i < end; i += 16) {
    int i1 = i + 4, i2 = i + 8, i3 = i + 12;
    bool h1 = i1 < end, h2 = i2 < end, h3 = i3 < end;
    int s0 = csrS[i];
    int s1 = h1 ? csrS[i1] : s0;
    int s2 = h2 ? csrS[i2] : s0;
    int s3 = h3 ? csrS[i3] : s0;
    uint2 pa0 = A2[(size_t)s0 * 16 + l16];
    uint2 pa1 = A2[(size_t)s1 * 16 + l16];
    uint2 pa2 = A2[(size_t)s2 * 16 + l16];
    uint2 pa3 = A2[(size_t)s3 * 16 + l16];
    float f[8];
    float dot0 = 0.f, dot1 = 0.f, dot2 = 0.f, dot3 = 0.f;
    unpack_fp8x4(pa0.x, f); unpack_fp8x4(pa0.y, f + 4);
    #pragma unroll
    for (int j = 0; j < 8; ++j) dot0 = fmaf(fmaxf(f[j] + bvals[j], 0.f), wv[j], dot0);
    unpack_fp8x4(pa1.x, f); unpack_fp8x4(pa1.y, f + 4);
    #pragma unroll
    for (int j = 0; j < 8; ++j) dot1 = fmaf(fmaxf(f[j] + bvals[j], 0.f), wv[j], dot1);
    unpack_fp8x4(pa2.x, f); unpack_fp8x4(pa2.y, f + 4);
    #pragma unroll
    for (int j = 0; j < 8; ++j) dot2 = fmaf(fmaxf(f[j] + bvals[j], 0.f), wv[j], dot2);
    unpack_fp8x4(pa3.x, f); unpack_fp8x4(pa3.y, f + 4);
    #pragma unroll
    for (int j = 0; j < 8; ++j) dot3 = fmaf(fmaxf(f[j] + bvals[j], 0.f), wv[j], dot3);
    #pragma unroll
    for (int o = 1; o <= 8; o <<= 1) {
      dot0 += __shfl_xor(dot0, o);
      dot1 += __shfl_xor(dot1, o);
      dot2 += __shfl_xor(dot2, o);
      dot3 += __shfl_xor(dot3, o);
    }
    if (l16 == 0) {
      pout[i] = dot0;
      if (h1) pout[i1] = dot1;
      if (h2) pout[i2] = dot2;
      if (h3) pout[i3] = dot3;
    }
  }
}

// --- finalize: out[e] = sigmoid(pout[rowptr[d] + repoff + pintra[e]] + b2) ---
__global__ __launch_bounds__(256) void edge_fin_k(const float* __restrict__ pout,
    const int* __restrict__ dst, const int* __restrict__ pintra,
    const int* __restrict__ rowptr, const int* __restrict__ cntR,
    const float* __restrict__ b2, float* __restrict__ out, int N, int E) {
  int t = blockIdx.x * 256 + threadIdx.x;
  if (t >= E) return;
  int d = dst[t];
  int r = t & 7;
  int p = rowptr[d] + cntR[(size_t)r * N + d] + pintra[t];
  float z = pout[p] + b2[0];
  out[t] = 1.f / (1.f + expf(-z));
}

extern "C" void kernel_launch(void* const* d_in, const int* in_sizes, int n_in,
                              void* d_out, int out_size, void* d_ws, size_t ws_size,
                              hipStream_t stream) {
  const float* x    = (const float*)d_in[0];
  const int*   ei   = (const int*)d_in[1];
  const float* W1   = (const float*)d_in[2];
  const float* b1   = (const float*)d_in[3];
  const float* g1   = (const float*)d_in[4];
  const float* be1  = (const float*)d_in[5];
  const float* m1   = (const float*)d_in[6];
  const float* v1   = (const float*)d_in[7];
  const float* W2   = (const float*)d_in[8];
  const float* b2   = (const float*)d_in[9];
  const float* g2   = (const float*)d_in[10];
  const float* be2  = (const float*)d_in[11];
  const float* m2   = (const float*)d_in[12];
  const float* v2   = (const float*)d_in[13];
  const float* epW1 = (const float*)d_in[14];
  const float* epb1 = (const float*)d_in[15];
  const float* epW2 = (const float*)d_in[16];
  const float* epb2 = (const float*)d_in[17];

  int N = in_sizes[0] / 128;
  int E = in_sizes[1] / 2;
  const int* src = ei;
  const int* dst = ei + E;

  char* w = (char*)d_ws;
  size_t off = 0;
  auto carve = [&](size_t bytes) {
    void* p = w + off;
    off = (off + bytes + 255) & ~(size_t)255;
    return p;
  };
  u8*  bufX8 = (u8*)carve((size_t)N * 128);       // XW' fp8 (layer1/layer2 gathers)
  u16* bufH  = (u16*)carve((size_t)N * 128 * 2);  // h1 -> h2 (bf16)
  u16* bufB  = (u16*)carve((size_t)N * 128 * 2);  // B (bf16)
  u8*  bufA8 = (u8*)carve((size_t)N * 128);       // A (fp8 e4m3)
  int*   cntR  = (int*)carve((size_t)8 * N * 4);  // replicated counters -> offsets
  int*   cnt   = (int*)carve((size_t)N * 4);
  int*   pintra= (int*)carve((size_t)E * 4);
  int*   rowptr= (int*)carve((size_t)(N + 1) * 4);
  float* dinv  = (float*)carve((size_t)N * 4);
  int*   csrS  = (int*)carve((size_t)E * 4);
  int*   bsum  = (int*)carve((size_t)1024 * 4);
  u16*   wsT   = (u16*)carve((size_t)4 * 16384 * 2);
  float* pout  = (float*)carve((size_t)E * 4);
  float* bnab  = (float*)carve((size_t)512 * 4);  // folded BN alpha/beta x2 layers
  (void)ws_size; (void)n_in; (void)out_size;

  int nb = (N + 255) / 256;
  int T = (E + 3) / 4;
  int tb = (T + 255) / 256;
  int eb = (E + 255) / 256;
  int rb = (8 * N + 255) / 256;

  clear_k<<<rb, 256, 0, stream>>>(cntR, 8 * N);
  prep_k<<<257, 256, 0, stream>>>(W1, W2, epW1, b1, g1, be1, m1, v1,
                                  b2, g2, be2, m2, v2, wsT, bnab);
  count_pos_k<<<eb, 256, 0, stream>>>(dst, cntR, pintra, N, E);
  rowsum_k<<<nb, 256, 0, stream>>>(cntR, cnt, dinv, N);
  blocksum_k<<<nb, 256, 0, stream>>>(cnt, bsum, N);
  scan_bsum_k<<<1, 1024, 0, stream>>>(bsum, nb);
  scan_final_k<<<nb, 256, 0, stream>>>(cnt, bsum, rowptr, N);
  fill_csr_k<<<tb, 256, 0, stream>>>(src, dst, rowptr, cntR, pintra, csrS, N, T, E);

  int gb = (N + 63) / 64;
  int an = (N + 15) / 16;   // agg: 16 nodes per block (16 lanes/node)
  int ab = (N + 3) / 4;     // edge pass: wave per node
  const u16* WtW1 = wsT;
  const u16* WtW2 = wsT + 16384;
  const u16* WtA  = wsT + 2 * 16384;
  const u16* WtB  = wsT + 3 * 16384;

  // layer 1: XW' = dinv * (x @ W1) -> fp8
  gemm_mfma_k<false, true, true><<<gb, 256, 0, stream>>>(x, WtW1, dinv, bufX8, N);
  agg_bn_relu_k<<<an, 256, 0, stream>>>(bufX8, rowptr, csrS, dinv, bnab,
                                        (uint4*)bufH, N);
  // layer 2
  gemm_mfma_k<true, true, true><<<gb, 256, 0, stream>>>(bufH, WtW2, dinv, bufX8, N);
  agg_bn_relu_k<<<an, 256, 0, stream>>>(bufX8, rowptr, csrS, dinv, bnab + 256,
                                        (uint4*)bufH, N);
  // edge predictor: A (fp8, +epb1) and B (bf16), fused
  gemm_mfma2_k<<<gb, 256, 0, stream>>>(bufH, WtA, WtB, epb1, bufA8, bufB, N);
  // edge MLP partial dots (coalesced writes), then finalize with sigmoid
  edge_pass_k<<<ab, 256, 0, stream>>>(bufA8, (const uint4*)bufB, rowptr, csrS,
                                      epW2, pout, N);
  edge_fin_k<<<eb, 256, 0, stream>>>(pout, dst, pintra, rowptr, cntR,
                                     epb2, (float*)d_out, N, E);
}

// Round 17
// 216.356 us; speedup vs baseline: 1.0246x; 1.0246x over previous
//
#include <hip/hip_runtime.h>
#include <math.h>

#define BN_EPS 1e-5f

typedef unsigned short u16;
typedef unsigned int u32;
typedef unsigned char u8;
typedef __attribute__((ext_vector_type(8))) short bf16x8;
typedef __attribute__((ext_vector_type(4))) float f32x4;
typedef __attribute__((ext_vector_type(2))) float f32x2;

__device__ __forceinline__ u16 f2bf(float f) {
  u32 u = __float_as_uint(f);
  u32 r = (u + 0x7fffu + ((u >> 16) & 1u)) >> 16;   // RNE
  return (u16)r;
}
__device__ __forceinline__ u32 packbf2(float x, float y) {
  return (u32)f2bf(x) | ((u32)f2bf(y) << 16);
}
__device__ __forceinline__ float lo_bf(u32 p) { return __uint_as_float(p << 16); }
__device__ __forceinline__ float hi_bf(u32 p) { return __uint_as_float(p & 0xffff0000u); }

__device__ __forceinline__ void unpack8(uint4 p, float* f) {
  f[0] = lo_bf(p.x); f[1] = hi_bf(p.x);
  f[2] = lo_bf(p.y); f[3] = hi_bf(p.y);
  f[4] = lo_bf(p.z); f[5] = hi_bf(p.z);
  f[6] = lo_bf(p.w); f[7] = hi_bf(p.w);
}

// fp8 e4m3 x4 unpack, packed 2-at-a-time (v_cvt_pk_f32_fp8)
__device__ __forceinline__ void unpack_fp8x4(u32 p, float* f) {
  f32x2 lo = __builtin_amdgcn_cvt_pk_f32_fp8((int)p, false);
  f32x2 hi = __builtin_amdgcn_cvt_pk_f32_fp8((int)p, true);
  f[0] = lo.x; f[1] = lo.y; f[2] = hi.x; f[3] = hi.y;
}
__device__ __forceinline__ u8 f2fp8(float o) {
  u32 pk = __builtin_amdgcn_cvt_pk_fp8_f32(o, o, 0, false);
  return (u8)(pk & 0xffu);
}

// ---------------- workspace clear ----------------
__global__ __launch_bounds__(256) void clear_k(int* __restrict__ p, int n) {
  int i = blockIdx.x * 256 + threadIdx.x;
  if (i < n) p[i] = 0;
}

// ---------------- CSR build (8-way replicated counters, 4-edge ILP) ----------------
// replica r = e & 7; pintra[e] = position within (replica, dst) bucket
__global__ __launch_bounds__(256) void count_pos_k(const int* __restrict__ dst,
                                                   int* __restrict__ cntR,
                                                   int* __restrict__ pintra,
                                                   int N, int T, int E) {
  int t = blockIdx.x * 256 + threadIdx.x;
  if (t >= T) return;
  int e0 = t, e1 = t + T, e2 = t + 2 * T, e3 = t + 3 * T;
  int d0 = (e0 < E) ? dst[e0] : -1;
  int d1 = (e1 < E) ? dst[e1] : -1;
  int d2 = (e2 < E) ? dst[e2] : -1;
  int d3 = (e3 < E) ? dst[e3] : -1;
  int p0 = (d0 >= 0) ? atomicAdd(&cntR[(size_t)(e0 & 7) * N + d0], 1) : 0;
  int p1 = (d1 >= 0) ? atomicAdd(&cntR[(size_t)(e1 & 7) * N + d1], 1) : 0;
  int p2 = (d2 >= 0) ? atomicAdd(&cntR[(size_t)(e2 & 7) * N + d2], 1) : 0;
  int p3 = (d3 >= 0) ? atomicAdd(&cntR[(size_t)(e3 & 7) * N + d3], 1) : 0;
  if (d0 >= 0) pintra[e0] = p0;
  if (d1 >= 0) pintra[e1] = p1;
  if (d2 >= 0) pintra[e2] = p2;
  if (d3 >= 0) pintra[e3] = p3;
}

// per-node: total over 8 replicas -> cnt, dinv; overwrite replicas with excl offsets
__global__ __launch_bounds__(256) void rowsum_k(int* __restrict__ cntR,
                                                int* __restrict__ cnt,
                                                float* __restrict__ dinv, int N) {
  int i = blockIdx.x * 256 + threadIdx.x;
  if (i >= N) return;
  int c[8];
  #pragma unroll
  for (int r = 0; r < 8; ++r) c[r] = cntR[(size_t)r * N + i];
  int run = 0;
  #pragma unroll
  for (int r = 0; r < 8; ++r) {
    int v = c[r];
    cntR[(size_t)r * N + i] = run;
    run += v;
  }
  cnt[i] = run;
  dinv[i] = rsqrtf((float)(run + 1));   // deg = in-degree + self-loop
}

__global__ __launch_bounds__(256) void blocksum_k(const int* __restrict__ cnt,
                                                  int* __restrict__ bsum, int n) {
  __shared__ int red[256];
  int tid = threadIdx.x;
  int i = blockIdx.x * 256 + tid;
  int v = (i < n) ? cnt[i] : 0;
  red[tid] = v;
  __syncthreads();
  for (int o = 128; o > 0; o >>= 1) {
    if (tid < o) red[tid] += red[tid + o];
    __syncthreads();
  }
  if (tid == 0) bsum[blockIdx.x] = red[0];
}

__global__ __launch_bounds__(1024) void scan_bsum_k(int* __restrict__ bsum, int nb) {
  __shared__ int part[1024];
  int tid = threadIdx.x;
  int v = (tid < nb) ? bsum[tid] : 0;
  part[tid] = v;
  __syncthreads();
  for (int o = 1; o < 1024; o <<= 1) {
    int t = (tid >= o) ? part[tid - o] : 0;
    __syncthreads();
    part[tid] += t;
    __syncthreads();
  }
  if (tid < nb) bsum[tid] = part[tid] - v;   // exclusive
}

// rowptr + fold rowptr into replica offsets: cntR[r][i] += rowptr[i]
__global__ __launch_bounds__(256) void scan_final_k(const int* __restrict__ cnt,
                                                    const int* __restrict__ bsum,
                                                    int* __restrict__ rowptr,
                                                    int* __restrict__ cntR, int n) {
  __shared__ int part[256];
  int tid = threadIdx.x;
  int i = blockIdx.x * 256 + tid;
  int v = (i < n) ? cnt[i] : 0;
  part[tid] = v;
  __syncthreads();
  for (int o = 1; o < 256; o <<= 1) {
    int t = (tid >= o) ? part[tid - o] : 0;
    __syncthreads();
    part[tid] += t;
    __syncthreads();
  }
  if (i < n) {
    int excl = part[tid] - v + bsum[blockIdx.x];
    rowptr[i] = excl;
    #pragma unroll
    for (int r = 0; r < 8; ++r) cntR[(size_t)r * n + i] += excl;
    if (i == n - 1) rowptr[n] = excl + v;
  }
}

// scatter 4B src per edge; slot = base[r][d] + pintra[e]  (ONE random lookup)
__global__ __launch_bounds__(256) void fill_csr_k(const int* __restrict__ src,
                                                  const int* __restrict__ dst,
                                                  const int* __restrict__ base,
                                                  const int* __restrict__ pintra,
                                                  int* __restrict__ csrS,
                                                  int N, int T, int E) {
  int t = blockIdx.x * 256 + threadIdx.x;
  if (t >= T) return;
  #pragma unroll
  for (int u = 0; u < 4; ++u) {
    int e = t + u * T;
    if (e < E) {
      int d = dst[e];
      int p = base[(size_t)(e & 7) * N + d] + pintra[e];
      csrS[p] = src[e];
    }
  }
}

// ---- prep: weights fp32->transposed bf16 (blocks 0..255) + BN fold (block 256) ----
__global__ __launch_bounds__(256) void prep_k(const float* __restrict__ W1,
    const float* __restrict__ W2, const float* __restrict__ epW1,
    const float* __restrict__ b1, const float* __restrict__ g1,
    const float* __restrict__ be1, const float* __restrict__ m1,
    const float* __restrict__ v1,
    const float* __restrict__ b2, const float* __restrict__ g2,
    const float* __restrict__ be2, const float* __restrict__ m2,
    const float* __restrict__ v2,
    u16* __restrict__ wout, float* __restrict__ bnout) {
  if (blockIdx.x < 256) {
    int t = blockIdx.x * 256 + threadIdx.x;   // 4 * 16384
    int m = t >> 14, r = t & 16383;
    int n = r >> 7, k = r & 127;
    const float* src = (m == 0) ? W1 : (m == 1) ? W2 : epW1 + (size_t)(m - 2) * 16384;
    wout[t] = f2bf(src[k * 128 + n]);
  } else {
    int t = threadIdx.x;
    int layer = t >> 7, c = t & 127;
    const float* bb = layer ? b2 : b1;
    const float* gg = layer ? g2 : g1;
    const float* ee = layer ? be2 : be1;
    const float* mm = layer ? m2 : m1;
    const float* vv = layer ? v2 : v1;
    float alpha = gg[c] * rsqrtf(vv[c] + BN_EPS);
    float beta = (bb[c] - mm[c]) * alpha + ee[c];
    bnout[layer * 256 + c] = alpha;
    bnout[layer * 256 + 128 + c] = beta;
  }
}

// ---- MFMA GEMM: Y[M,128] = (X[M,128] @ W) (* dinv[row]); out bf16 or fp8 ----
template<bool BF16IN, bool SCALE, bool FP8OUT>
__global__ __launch_bounds__(256) void gemm_mfma_k(const void* __restrict__ Xv,
    const u16* __restrict__ Wt, const float* __restrict__ dinv,
    void* __restrict__ Yv, int M) {
  __shared__ u16 Xs[64][136];
  __shared__ u16 Ws[128][136];
  int tid = threadIdx.x;
  int row0 = blockIdx.x * 64;
  for (int i = tid; i < 2048; i += 256) {
    int n = i >> 4, c8 = i & 15;
    uint4 v = ((const uint4*)Wt)[i];
    *(uint4*)&Ws[n][c8 * 8] = v;
  }
  for (int i = tid; i < 1024; i += 256) {
    int r = i >> 4, c8 = i & 15;
    int gr = row0 + r;
    uint4 v = make_uint4(0u, 0u, 0u, 0u);
    if (gr < M) {
      if (BF16IN) {
        v = ((const uint4*)Xv)[(size_t)gr * 16 + c8];
      } else {
        const float* Xf = (const float*)Xv;
        float4 f0 = ((const float4*)Xf)[(size_t)gr * 32 + c8 * 2];
        float4 f1 = ((const float4*)Xf)[(size_t)gr * 32 + c8 * 2 + 1];
        v.x = packbf2(f0.x, f0.y); v.y = packbf2(f0.z, f0.w);
        v.z = packbf2(f1.x, f1.y); v.w = packbf2(f1.z, f1.w);
      }
    }
    *(uint4*)&Xs[r][c8 * 8] = v;
  }
  __syncthreads();
  int w = tid >> 6, l = tid & 63;
  int lr = l & 15, kq = l >> 4;
  bf16x8 a[4];
  #pragma unroll
  for (int kk = 0; kk < 4; ++kk)
    a[kk] = *(const bf16x8*)&Xs[w * 16 + lr][kk * 32 + kq * 8];
  float sc[4];
  #pragma unroll
  for (int r = 0; r < 4; ++r) {
    int grow = row0 + w * 16 + kq * 4 + r;
    sc[r] = (SCALE && grow < M) ? dinv[grow] : 1.f;
  }
  #pragma unroll
  for (int ct = 0; ct < 8; ++ct) {
    f32x4 c = {0.f, 0.f, 0.f, 0.f};
    #pragma unroll
    for (int kk = 0; kk < 4; ++kk) {
      bf16x8 b = *(const bf16x8*)&Ws[ct * 16 + lr][kk * 32 + kq * 8];
      c = __builtin_amdgcn_mfma_f32_16x16x32_bf16(a[kk], b, c, 0, 0, 0);
    }
    int n = ct * 16 + lr;
    #pragma unroll
    for (int r = 0; r < 4; ++r) {
      int grow = row0 + w * 16 + kq * 4 + r;
      if (grow < M) {
        float o = c[r];
        if (SCALE) o *= sc[r];
        if (FP8OUT) {
          ((u8*)Yv)[(size_t)grow * 128 + n] = f2fp8(o);
        } else {
          ((u16*)Yv)[(size_t)grow * 128 + n] = f2bf(o);
        }
      }
    }
  }
}

// ---- fused double GEMM (edge predictor): A out fp8 e4m3 (+bias), B out bf16 ----
__global__ __launch_bounds__(256) void gemm_mfma2_k(const u16* __restrict__ X,
    const u16* __restrict__ WtA, const u16* __restrict__ WtB,
    const float* __restrict__ bias, u8* __restrict__ YA8, u16* __restrict__ YB, int M) {
  __shared__ u16 Xs[64][136];
  __shared__ u16 Ws[128][136];
  int tid = threadIdx.x;
  int row0 = blockIdx.x * 64;
  for (int i = tid; i < 1024; i += 256) {
    int r = i >> 4, c8 = i & 15;
    int gr = row0 + r;
    uint4 v = make_uint4(0u, 0u, 0u, 0u);
    if (gr < M) v = ((const uint4*)X)[(size_t)gr * 16 + c8];
    *(uint4*)&Xs[r][c8 * 8] = v;
  }
  __syncthreads();
  int w = tid >> 6, l = tid & 63;
  int lr = l & 15, kq = l >> 4;
  bf16x8 a[4];
  #pragma unroll
  for (int kk = 0; kk < 4; ++kk)
    a[kk] = *(const bf16x8*)&Xs[w * 16 + lr][kk * 32 + kq * 8];

  for (int m = 0; m < 2; ++m) {
    const u16* Wt = m ? WtB : WtA;
    __syncthreads();
    for (int i = tid; i < 2048; i += 256) {
      int n = i >> 4, c8 = i & 15;
      uint4 v = ((const uint4*)Wt)[i];
      *(uint4*)&Ws[n][c8 * 8] = v;
    }
    __syncthreads();
    #pragma unroll
    for (int ct = 0; ct < 8; ++ct) {
      f32x4 c = {0.f, 0.f, 0.f, 0.f};
      #pragma unroll
      for (int kk = 0; kk < 4; ++kk) {
        bf16x8 b = *(const bf16x8*)&Ws[ct * 16 + lr][kk * 32 + kq * 8];
        c = __builtin_amdgcn_mfma_f32_16x16x32_bf16(a[kk], b, c, 0, 0, 0);
      }
      int n = ct * 16 + lr;
      if (m == 0) {
        float bv = bias[n];
        #pragma unroll
        for (int r = 0; r < 4; ++r) {
          int grow = row0 + w * 16 + kq * 4 + r;
          if (grow < M) YA8[(size_t)grow * 128 + n] = f2fp8(c[r] + bv);
        }
      } else {
        #pragma unroll
        for (int r = 0; r < 4; ++r) {
          int grow = row0 + w * 16 + kq * 4 + r;
          if (grow < M) YB[(size_t)grow * 128 + n] = f2bf(c[r]);
        }
      }
    }
  }
}

// --- agg: 16 lanes/node (4 nodes/wave); masked 8-deep gather; folded BN ---
__global__ __launch_bounds__(256) void agg_bn_relu_k(const u8* __restrict__ XW8,
    const int* __restrict__ rowptr, const int* __restrict__ csrS,
    const float* __restrict__ dinv, const float* __restrict__ ab,
    uint4* __restrict__ H4, int n) {
  int node = (blockIdx.x * 256 + threadIdx.x) >> 4;
  if (node >= n) return;
  int l16 = threadIdx.x & 15;
  int beg = rowptr[node], end = rowptr[node + 1];
  const uint2* X2 = (const uint2*)XW8;   // row = 16 uint2 (128B)
  float ac[8];
  #pragma unroll
  for (int j = 0; j < 8; ++j) ac[j] = 0.f;
  float f[8];
  for (int i = beg; i < end; i += 8) {
    int s[8];
    bool h[8];
    #pragma unroll
    for (int u = 0; u < 8; ++u) {
      int idx = i + u;
      h[u] = idx < end;
      s[u] = h[u] ? csrS[idx] : csrS[i];
    }
    uint2 p[8];
    #pragma unroll
    for (int u = 0; u < 8; ++u) p[u] = X2[(size_t)s[u] * 16 + l16];
    #pragma unroll
    for (int u = 0; u < 8; ++u) {
      if (h[u]) {
        unpack_fp8x4(p[u].x, f); unpack_fp8x4(p[u].y, f + 4);
        #pragma unroll
        for (int j = 0; j < 8; ++j) ac[j] += f[j];
      }
    }
  }
  {
    uint2 p = X2[(size_t)node * 16 + l16];
    unpack_fp8x4(p.x, f); unpack_fp8x4(p.y, f + 4);
    #pragma unroll
    for (int j = 0; j < 8; ++j) ac[j] += f[j];
  }
  float dn = dinv[node];
  int c = l16 * 8;
  float4 a0 = *(const float4*)&ab[c];
  float4 a1 = *(const float4*)&ab[c + 4];
  float4 t0 = *(const float4*)&ab[128 + c];
  float4 t1 = *(const float4*)&ab[128 + c + 4];
  float al[8] = {a0.x, a0.y, a0.z, a0.w, a1.x, a1.y, a1.z, a1.w};
  float bt[8] = {t0.x, t0.y, t0.z, t0.w, t1.x, t1.y, t1.z, t1.w};
  u32 out[4];
  #pragma unroll
  for (int j2 = 0; j2 < 4; ++j2) {
    float o0 = fmaxf(fmaf(ac[2*j2]     * dn, al[2*j2],     bt[2*j2]),     0.f);
    float o1 = fmaxf(fmaf(ac[2*j2 + 1] * dn, al[2*j2 + 1], bt[2*j2 + 1]), 0.f);
    out[j2] = packbf2(o0, o1);
  }
  H4[(size_t)node * 16 + l16] = make_uint4(out[0], out[1], out[2], out[3]);
}

// --- edge pass: node-major; B[d] bf16 in regs; gather A[s] fp8; 4 loads in flight ---
__global__ __launch_bounds__(256) void edge_pass_k(const u8* __restrict__ A8,
    const uint4* __restrict__ B4, const int* __restrict__ rowptr,
    const int* __restrict__ csrS, const float* __restrict__ w2,
    float* __restrict__ pout, int n) {
  int node = (blockIdx.x * 256 + threadIdx.x) >> 6;
  if (node >= n) return;
  int lane = threadIdx.x & 63;
  int sub = lane >> 4, l16 = lane & 15;
  int beg = rowptr[node], end = rowptr[node + 1];
  if (beg >= end) return;
  float bvals[8];
  unpack8(B4[(size_t)node * 16 + l16], bvals);
  int c = l16 * 8;
  float4 w0 = *(const float4*)&w2[c];
  float4 w1 = *(const float4*)&w2[c + 4];
  float wv[8] = {w0.x, w0.y, w0.z, w0.w, w1.x, w1.y, w1.z, w1.w};
  const uint2* A2 = (const uint2*)A8;
  for (int i = beg + sub; i < end; i += 16) {
    int i1 = i + 4, i2 = i + 8, i3 = i + 12;
    bool h1 = i1 < end, h2 = i2 < end, h3 = i3 < end;
    int s0 = csrS[i];
    int s1 = h1 ? csrS[i1] : s0;
    int s2 = h2 ? csrS[i2] : s0;
    int s3 = h3 ? csrS[i3] : s0;
    uint2 pa0 = A2[(size_t)s0 * 16 + l16];
    uint2 pa1 = A2[(size_t)s1 * 16 + l16];
    uint2 pa2 = A2[(size_t)s2 * 16 + l16];
    uint2 pa3 = A2[(size_t)s3 * 16 + l16];
    float f[8];
    float dot0 = 0.f, dot1 = 0.f, dot2 = 0.f, dot3 = 0.f;
    unpack_fp8x4(pa0.x, f); unpack_fp8x4(pa0.y, f + 4);
    #pragma unroll
    for (int j = 0; j < 8; ++j) dot0 = fmaf(fmaxf(f[j] + bvals[j], 0.f), wv[j], dot0);
    unpack_fp8x4(pa1.x, f); unpack_fp8x4(pa1.y, f + 4);
    #pragma unroll
    for (int j = 0; j < 8; ++j) dot1 = fmaf(fmaxf(f[j] + bvals[j], 0.f), wv[j], dot1);
    unpack_fp8x4(pa2.x, f); unpack_fp8x4(pa2.y, f + 4);
    #pragma unroll
    for (int j = 0; j < 8; ++j) dot2 = fmaf(fmaxf(f[j] + bvals[j], 0.f), wv[j], dot2);
    unpack_fp8x4(pa3.x, f); unpack_fp8x4(pa3.y, f + 4);
    #pragma unroll
    for (int j = 0; j < 8; ++j) dot3 = fmaf(fmaxf(f[j] + bvals[j], 0.f), wv[j], dot3);
    #pragma unroll
    for (int o = 1; o <= 8; o <<= 1) {
      dot0 += __shfl_xor(dot0, o);
      dot1 += __shfl_xor(dot1, o);
      dot2 += __shfl_xor(dot2, o);
      dot3 += __shfl_xor(dot3, o);
    }
    if (l16 == 0) {
      pout[i] = dot0;
      if (h1) pout[i1] = dot1;
      if (h2) pout[i2] = dot2;
      if (h3) pout[i3] = dot3;
    }
  }
}

// --- finalize: out[e] = sigmoid(pout[base[r][d] + pintra[e]] + b2) ---
__global__ __launch_bounds__(256) void edge_fin_k(const float* __restrict__ pout,
    const int* __restrict__ dst, const int* __restrict__ pintra,
    const int* __restrict__ base, const float* __restrict__ b2,
    float* __restrict__ out, int N, int E) {
  int t = blockIdx.x * 256 + threadIdx.x;
  if (t >= E) return;
  int d = dst[t];
  int p = base[(size_t)(t & 7) * N + d] + pintra[t];
  float z = pout[p] + b2[0];
  out[t] = 1.f / (1.f + expf(-z));
}

extern "C" void kernel_launch(void* const* d_in, const int* in_sizes, int n_in,
                              void* d_out, int out_size, void* d_ws, size_t ws_size,
                              hipStream_t stream) {
  const float* x    = (const float*)d_in[0];
  const int*   ei   = (const int*)d_in[1];
  const float* W1   = (const float*)d_in[2];
  const float* b1   = (const float*)d_in[3];
  const float* g1   = (const float*)d_in[4];
  const float* be1  = (const float*)d_in[5];
  const float* m1   = (const float*)d_in[6];
  const float* v1   = (const float*)d_in[7];
  const float* W2   = (const float*)d_in[8];
  const float* b2   = (const float*)d_in[9];
  const float* g2   = (const float*)d_in[10];
  const float* be2  = (const float*)d_in[11];
  const float* m2   = (const float*)d_in[12];
  const float* v2   = (const float*)d_in[13];
  const float* epW1 = (const float*)d_in[14];
  const float* epb1 = (const float*)d_in[15];
  const float* epW2 = (const float*)d_in[16];
  const float* epb2 = (const float*)d_in[17];

  int N = in_sizes[0] / 128;
  int E = in_sizes[1] / 2;
  const int* src = ei;
  const int* dst = ei + E;

  char* w = (char*)d_ws;
  size_t off = 0;
  auto carve = [&](size_t bytes) {
    void* p = w + off;
    off = (off + bytes + 255) & ~(size_t)255;
    return p;
  };
  u8*  bufX8 = (u8*)carve((size_t)N * 128);       // XW' fp8 (layer1/layer2 gathers)
  u16* bufH  = (u16*)carve((size_t)N * 128 * 2);  // h1 -> h2 (bf16)
  u16* bufB  = (u16*)carve((size_t)N * 128 * 2);  // B (bf16)
  u8*  bufA8 = (u8*)carve((size_t)N * 128);       // A (fp8 e4m3)
  int*   cntR  = (int*)carve((size_t)8 * N * 4);  // replicated counters -> slot bases
  int*   cnt   = (int*)carve((size_t)N * 4);
  int*   pintra= (int*)carve((size_t)E * 4);
  int*   rowptr= (int*)carve((size_t)(N + 1) * 4);
  float* dinv  = (float*)carve((size_t)N * 4);
  int*   csrS  = (int*)carve((size_t)E * 4);
  int*   bsum  = (int*)carve((size_t)1024 * 4);
  u16*   wsT   = (u16*)carve((size_t)4 * 16384 * 2);
  float* pout  = (float*)carve((size_t)E * 4);
  float* bnab  = (float*)carve((size_t)512 * 4);  // folded BN alpha/beta x2 layers
  (void)ws_size; (void)n_in; (void)out_size;

  int nb = (N + 255) / 256;
  int T = (E + 3) / 4;
  int tb = (T + 255) / 256;
  int eb = (E + 255) / 256;
  int rb = (8 * N + 255) / 256;

  clear_k<<<rb, 256, 0, stream>>>(cntR, 8 * N);
  prep_k<<<257, 256, 0, stream>>>(W1, W2, epW1, b1, g1, be1, m1, v1,
                                  b2, g2, be2, m2, v2, wsT, bnab);
  count_pos_k<<<tb, 256, 0, stream>>>(dst, cntR, pintra, N, T, E);
  rowsum_k<<<nb, 256, 0, stream>>>(cntR, cnt, dinv, N);
  blocksum_k<<<nb, 256, 0, stream>>>(cnt, bsum, N);
  scan_bsum_k<<<1, 1024, 0, stream>>>(bsum, nb);
  scan_final_k<<<nb, 256, 0, stream>>>(cnt, bsum, rowptr, cntR, N);
  fill_csr_k<<<tb, 256, 0, stream>>>(src, dst, cntR, pintra, csrS, N, T, E);

  int gb = (N + 63) / 64;
  int an = (N + 15) / 16;   // agg: 16 nodes per block (16 lanes/node)
  int ab = (N + 3) / 4;     // edge pass: wave per node
  const u16* WtW1 = wsT;
  const u16* WtW2 = wsT + 16384;
  const u16* WtA  = wsT + 2 * 16384;
  const u16* WtB  = wsT + 3 * 16384;

  // layer 1: XW' = dinv * (x @ W1) -> fp8
  gemm_mfma_k<false, true, true><<<gb, 256, 0, stream>>>(x, WtW1, dinv, bufX8, N);
  agg_bn_relu_k<<<an, 256, 0, stream>>>(bufX8, rowptr, csrS, dinv, bnab,
                                        (uint4*)bufH, N);
  // layer 2
  gemm_mfma_k<true, true, true><<<gb, 256, 0, stream>>>(bufH, WtW2, dinv, bufX8, N);
  agg_bn_relu_k<<<an, 256, 0, stream>>>(bufX8, rowptr, csrS, dinv, bnab + 256,
                                        (uint4*)bufH, N);
  // edge predictor: A (fp8, +epb1) and B (bf16), fused
  gemm_mfma2_k<<<gb, 256, 0, stream>>>(bufH, WtA, WtB, epb1, bufA8, bufB, N);
  // edge MLP partial dots (coalesced writes), then finalize with sigmoid
  edge_pass_k<<<ab, 256, 0, stream>>>(bufA8, (const uint4*)bufB, rowptr, csrS,
                                      epW2, pout, N);
  edge_fin_k<<<eb, 256, 0, stream>>>(pout, dst, pintra, cntR,
                                     epb2, (float*)d_out, N, E);
}

// Round 18
// 211.099 us; speedup vs baseline: 1.0501x; 1.0249x over previous
//
#include <hip/hip_runtime.h>
#include <math.h>

#define BN_EPS 1e-5f

typedef unsigned short u16;
typedef unsigned int u32;
typedef unsigned char u8;
typedef __attribute__((ext_vector_type(8))) short bf16x8;
typedef __attribute__((ext_vector_type(4))) float f32x4;
typedef __attribute__((ext_vector_type(2))) float f32x2;

__device__ __forceinline__ u16 f2bf(float f) {
  u32 u = __float_as_uint(f);
  u32 r = (u + 0x7fffu + ((u >> 16) & 1u)) >> 16;   // RNE
  return (u16)r;
}
__device__ __forceinline__ u32 packbf2(float x, float y) {
  return (u32)f2bf(x) | ((u32)f2bf(y) << 16);
}
__device__ __forceinline__ float lo_bf(u32 p) { return __uint_as_float(p << 16); }
__device__ __forceinline__ float hi_bf(u32 p) { return __uint_as_float(p & 0xffff0000u); }

__device__ __forceinline__ void unpack8(uint4 p, float* f) {
  f[0] = lo_bf(p.x); f[1] = hi_bf(p.x);
  f[2] = lo_bf(p.y); f[3] = hi_bf(p.y);
  f[4] = lo_bf(p.z); f[5] = hi_bf(p.z);
  f[6] = lo_bf(p.w); f[7] = hi_bf(p.w);
}

// fp8 e4m3 x4 unpack, packed 2-at-a-time (v_cvt_pk_f32_fp8)
__device__ __forceinline__ void unpack_fp8x4(u32 p, float* f) {
  f32x2 lo = __builtin_amdgcn_cvt_pk_f32_fp8((int)p, false);
  f32x2 hi = __builtin_amdgcn_cvt_pk_f32_fp8((int)p, true);
  f[0] = lo.x; f[1] = lo.y; f[2] = hi.x; f[3] = hi.y;
}
__device__ __forceinline__ u8 f2fp8(float o) {
  u32 pk = __builtin_amdgcn_cvt_pk_fp8_f32(o, o, 0, false);
  return (u8)(pk & 0xffu);
}

// ---------------- workspace clear ----------------
__global__ __launch_bounds__(256) void clear_k(int* __restrict__ p, int n) {
  int i = blockIdx.x * 256 + threadIdx.x;
  if (i < n) p[i] = 0;
}

// ---------------- CSR build ----------------
__global__ __launch_bounds__(256) void count_pos_k(const int* __restrict__ dst,
                                                   int* __restrict__ cnt,
                                                   int* __restrict__ pintra,
                                                   int T, int E) {
  int t = blockIdx.x * 256 + threadIdx.x;
  if (t >= T) return;
  int e0 = t, e1 = t + T, e2 = t + 2 * T, e3 = t + 3 * T;
  int d0 = (e0 < E) ? dst[e0] : -1;
  int d1 = (e1 < E) ? dst[e1] : -1;
  int d2 = (e2 < E) ? dst[e2] : -1;
  int d3 = (e3 < E) ? dst[e3] : -1;
  int p0 = (d0 >= 0) ? atomicAdd(&cnt[d0], 1) : 0;
  int p1 = (d1 >= 0) ? atomicAdd(&cnt[d1], 1) : 0;
  int p2 = (d2 >= 0) ? atomicAdd(&cnt[d2], 1) : 0;
  int p3 = (d3 >= 0) ? atomicAdd(&cnt[d3], 1) : 0;
  if (d0 >= 0) pintra[e0] = p0;
  if (d1 >= 0) pintra[e1] = p1;
  if (d2 >= 0) pintra[e2] = p2;
  if (d3 >= 0) pintra[e3] = p3;
}

__global__ __launch_bounds__(256) void blocksum_k(const int* __restrict__ cnt,
                                                  int* __restrict__ bsum, int n) {
  __shared__ int red[256];
  int tid = threadIdx.x;
  int i = blockIdx.x * 256 + tid;
  int v = (i < n) ? cnt[i] : 0;
  red[tid] = v;
  __syncthreads();
  for (int o = 128; o > 0; o >>= 1) {
    if (tid < o) red[tid] += red[tid + o];
    __syncthreads();
  }
  if (tid == 0) bsum[blockIdx.x] = red[0];
}

__global__ __launch_bounds__(1024) void scan_bsum_k(int* __restrict__ bsum, int nb) {
  __shared__ int part[1024];
  int tid = threadIdx.x;
  int v = (tid < nb) ? bsum[tid] : 0;
  part[tid] = v;
  __syncthreads();
  for (int o = 1; o < 1024; o <<= 1) {
    int t = (tid >= o) ? part[tid - o] : 0;
    __syncthreads();
    part[tid] += t;
    __syncthreads();
  }
  if (tid < nb) bsum[tid] = part[tid] - v;   // exclusive
}

__global__ __launch_bounds__(256) void scan_final_k(const int* __restrict__ cnt,
                                                    const int* __restrict__ bsum,
                                                    int* __restrict__ rowptr,
                                                    float* __restrict__ dinv, int n) {
  __shared__ int part[256];
  int tid = threadIdx.x;
  int i = blockIdx.x * 256 + tid;
  int v = (i < n) ? cnt[i] : 0;
  part[tid] = v;
  __syncthreads();
  for (int o = 1; o < 256; o <<= 1) {
    int t = (tid >= o) ? part[tid - o] : 0;
    __syncthreads();
    part[tid] += t;
    __syncthreads();
  }
  if (i < n) {
    int excl = part[tid] - v + bsum[blockIdx.x];
    rowptr[i] = excl;
    dinv[i] = rsqrtf((float)(v + 1));   // deg = in-degree + self-loop
    if (i == n - 1) rowptr[n] = excl + v;
  }
}

// scatter 4B src per edge; eid recoverable as rowptr[dst[e]] + pintra[e]
__global__ __launch_bounds__(256) void fill_csr_k(const int* __restrict__ src,
                                                  const int* __restrict__ dst,
                                                  const int* __restrict__ rowptr,
                                                  const int* __restrict__ pintra,
                                                  int* __restrict__ csrS, int T, int E) {
  int t = blockIdx.x * 256 + threadIdx.x;
  if (t >= T) return;
  #pragma unroll
  for (int u = 0; u < 4; ++u) {
    int e = t + u * T;
    if (e < E) {
      int d = dst[e];
      int p = rowptr[d] + pintra[e];
      csrS[p] = src[e];
    }
  }
}

// ---- prep: weights fp32->transposed bf16 (blocks 0..255) + BN fold (block 256) ----
__global__ __launch_bounds__(256) void prep_k(const float* __restrict__ W1,
    const float* __restrict__ W2, const float* __restrict__ epW1,
    const float* __restrict__ b1, const float* __restrict__ g1,
    const float* __restrict__ be1, const float* __restrict__ m1,
    const float* __restrict__ v1,
    const float* __restrict__ b2, const float* __restrict__ g2,
    const float* __restrict__ be2, const float* __restrict__ m2,
    const float* __restrict__ v2,
    u16* __restrict__ wout, float* __restrict__ bnout) {
  if (blockIdx.x < 256) {
    int t = blockIdx.x * 256 + threadIdx.x;   // 4 * 16384
    int m = t >> 14, r = t & 16383;
    int n = r >> 7, k = r & 127;
    const float* src = (m == 0) ? W1 : (m == 1) ? W2 : epW1 + (size_t)(m - 2) * 16384;
    wout[t] = f2bf(src[k * 128 + n]);
  } else {
    int t = threadIdx.x;
    int layer = t >> 7, c = t & 127;
    const float* bb = layer ? b2 : b1;
    const float* gg = layer ? g2 : g1;
    const float* ee = layer ? be2 : be1;
    const float* mm = layer ? m2 : m1;
    const float* vv = layer ? v2 : v1;
    float alpha = gg[c] * rsqrtf(vv[c] + BN_EPS);
    float beta = (bb[c] - mm[c]) * alpha + ee[c];
    bnout[layer * 256 + c] = alpha;
    bnout[layer * 256 + 128 + c] = beta;
  }
}

// ---- MFMA GEMM: Y[M,128] = (X[M,128] @ W) (* dinv[row]); out bf16 or fp8 ----
template<bool BF16IN, bool SCALE, bool FP8OUT>
__global__ __launch_bounds__(256) void gemm_mfma_k(const void* __restrict__ Xv,
    const u16* __restrict__ Wt, const float* __restrict__ dinv,
    void* __restrict__ Yv, int M) {
  __shared__ u16 Xs[64][136];
  __shared__ u16 Ws[128][136];
  int tid = threadIdx.x;
  int row0 = blockIdx.x * 64;
  for (int i = tid; i < 2048; i += 256) {
    int n = i >> 4, c8 = i & 15;
    uint4 v = ((const uint4*)Wt)[i];
    *(uint4*)&Ws[n][c8 * 8] = v;
  }
  for (int i = tid; i < 1024; i += 256) {
    int r = i >> 4, c8 = i & 15;
    int gr = row0 + r;
    uint4 v = make_uint4(0u, 0u, 0u, 0u);
    if (gr < M) {
      if (BF16IN) {
        v = ((const uint4*)Xv)[(size_t)gr * 16 + c8];
      } else {
        const float* Xf = (const float*)Xv;
        float4 f0 = ((const float4*)Xf)[(size_t)gr * 32 + c8 * 2];
        float4 f1 = ((const float4*)Xf)[(size_t)gr * 32 + c8 * 2 + 1];
        v.x = packbf2(f0.x, f0.y); v.y = packbf2(f0.z, f0.w);
        v.z = packbf2(f1.x, f1.y); v.w = packbf2(f1.z, f1.w);
      }
    }
    *(uint4*)&Xs[r][c8 * 8] = v;
  }
  __syncthreads();
  int w = tid >> 6, l = tid & 63;
  int lr = l & 15, kq = l >> 4;
  bf16x8 a[4];
  #pragma unroll
  for (int kk = 0; kk < 4; ++kk)
    a[kk] = *(const bf16x8*)&Xs[w * 16 + lr][kk * 32 + kq * 8];
  float sc[4];
  #pragma unroll
  for (int r = 0; r < 4; ++r) {
    int grow = row0 + w * 16 + kq * 4 + r;
    sc[r] = (SCALE && grow < M) ? dinv[grow] : 1.f;
  }
  #pragma unroll
  for (int ct = 0; ct < 8; ++ct) {
    f32x4 c = {0.f, 0.f, 0.f, 0.f};
    #pragma unroll
    for (int kk = 0; kk < 4; ++kk) {
      bf16x8 b = *(const bf16x8*)&Ws[ct * 16 + lr][kk * 32 + kq * 8];
      c = __builtin_amdgcn_mfma_f32_16x16x32_bf16(a[kk], b, c, 0, 0, 0);
    }
    int n = ct * 16 + lr;
    #pragma unroll
    for (int r = 0; r < 4; ++r) {
      int grow = row0 + w * 16 + kq * 4 + r;
      if (grow < M) {
        float o = c[r];
        if (SCALE) o *= sc[r];
        if (FP8OUT) {
          ((u8*)Yv)[(size_t)grow * 128 + n] = f2fp8(o);
        } else {
          ((u16*)Yv)[(size_t)grow * 128 + n] = f2bf(o);
        }
      }
    }
  }
}

// ---- fused double GEMM (edge predictor): A out fp8 e4m3 (+bias), B out bf16 ----
__global__ __launch_bounds__(256) void gemm_mfma2_k(const u16* __restrict__ X,
    const u16* __restrict__ WtA, const u16* __restrict__ WtB,
    const float* __restrict__ bias, u8* __restrict__ YA8, u16* __restrict__ YB, int M) {
  __shared__ u16 Xs[64][136];
  __shared__ u16 Ws[128][136];
  int tid = threadIdx.x;
  int row0 = blockIdx.x * 64;
  for (int i = tid; i < 1024; i += 256) {
    int r = i >> 4, c8 = i & 15;
    int gr = row0 + r;
    uint4 v = make_uint4(0u, 0u, 0u, 0u);
    if (gr < M) v = ((const uint4*)X)[(size_t)gr * 16 + c8];
    *(uint4*)&Xs[r][c8 * 8] = v;
  }
  __syncthreads();
  int w = tid >> 6, l = tid & 63;
  int lr = l & 15, kq = l >> 4;
  bf16x8 a[4];
  #pragma unroll
  for (int kk = 0; kk < 4; ++kk)
    a[kk] = *(const bf16x8*)&Xs[w * 16 + lr][kk * 32 + kq * 8];

  for (int m = 0; m < 2; ++m) {
    const u16* Wt = m ? WtB : WtA;
    __syncthreads();
    for (int i = tid; i < 2048; i += 256) {
      int n = i >> 4, c8 = i & 15;
      uint4 v = ((const uint4*)Wt)[i];
      *(uint4*)&Ws[n][c8 * 8] = v;
    }
    __syncthreads();
    #pragma unroll
    for (int ct = 0; ct < 8; ++ct) {
      f32x4 c = {0.f, 0.f, 0.f, 0.f};
      #pragma unroll
      for (int kk = 0; kk < 4; ++kk) {
        bf16x8 b = *(const bf16x8*)&Ws[ct * 16 + lr][kk * 32 + kq * 8];
        c = __builtin_amdgcn_mfma_f32_16x16x32_bf16(a[kk], b, c, 0, 0, 0);
      }
      int n = ct * 16 + lr;
      if (m == 0) {
        float bv = bias[n];
        #pragma unroll
        for (int r = 0; r < 4; ++r) {
          int grow = row0 + w * 16 + kq * 4 + r;
          if (grow < M) YA8[(size_t)grow * 128 + n] = f2fp8(c[r] + bv);
        }
      } else {
        #pragma unroll
        for (int r = 0; r < 4; ++r) {
          int grow = row0 + w * 16 + kq * 4 + r;
          if (grow < M) YB[(size_t)grow * 128 + n] = f2bf(c[r]);
        }
      }
    }
  }
}

// --- agg: 16 lanes/node (4 nodes/wave); masked 8-deep gather; folded BN ---
__global__ __launch_bounds__(256) void agg_bn_relu_k(const u8* __restrict__ XW8,
    const int* __restrict__ rowptr, const int* __restrict__ csrS,
    const float* __restrict__ dinv, const float* __restrict__ ab,
    uint4* __restrict__ H4, int n) {
  int node = (blockIdx.x * 256 + threadIdx.x) >> 4;
  if (node >= n) return;
  int l16 = threadIdx.x & 15;
  int beg = rowptr[node], end = rowptr[node + 1];
  const uint2* X2 = (const uint2*)XW8;   // row = 16 uint2 (128B)
  float ac[8];
  #pragma unroll
  for (int j = 0; j < 8; ++j) ac[j] = 0.f;
  float f[8];
  for (int i = beg; i < end; i += 8) {
    int s[8];
    bool h[8];
    #pragma unroll
    for (int u = 0; u < 8; ++u) {
      int idx = i + u;
      h[u] = idx < end;
      s[u] = h[u] ? csrS[idx] : csrS[i];
    }
    uint2 p[8];
    #pragma unroll
    for (int u = 0; u < 8; ++u) p[u] = X2[(size_t)s[u] * 16 + l16];
    #pragma unroll
    for (int u = 0; u < 8; ++u) {
      if (h[u]) {
        unpack_fp8x4(p[u].x, f); unpack_fp8x4(p[u].y, f + 4);
        #pragma unroll
        for (int j = 0; j < 8; ++j) ac[j] += f[j];
      }
    }
  }
  {
    uint2 p = X2[(size_t)node * 16 + l16];
    unpack_fp8x4(p.x, f); unpack_fp8x4(p.y, f + 4);
    #pragma unroll
    for (int j = 0; j < 8; ++j) ac[j] += f[j];
  }
  float dn = dinv[node];
  int c = l16 * 8;
  float4 a0 = *(const float4*)&ab[c];
  float4 a1 = *(const float4*)&ab[c + 4];
  float4 t0 = *(const float4*)&ab[128 + c];
  float4 t1 = *(const float4*)&ab[128 + c + 4];
  float al[8] = {a0.x, a0.y, a0.z, a0.w, a1.x, a1.y, a1.z, a1.w};
  float bt[8] = {t0.x, t0.y, t0.z, t0.w, t1.x, t1.y, t1.z, t1.w};
  u32 out[4];
  #pragma unroll
  for (int j2 = 0; j2 < 4; ++j2) {
    float o0 = fmaxf(fmaf(ac[2*j2]     * dn, al[2*j2],     bt[2*j2]),     0.f);
    float o1 = fmaxf(fmaf(ac[2*j2 + 1] * dn, al[2*j2 + 1], bt[2*j2 + 1]), 0.f);
    out[j2] = packbf2(o0, o1);
  }
  H4[(size_t)node * 16 + l16] = make_uint4(out[0], out[1], out[2], out[3]);
}

// --- edge pass: node-major; B[d] bf16 in regs; gather A[s] fp8; 4 loads in flight ---
__global__ __launch_bounds__(256) void edge_pass_k(const u8* __restrict__ A8,
    const uint4* __restrict__ B4, const int* __restrict__ rowptr,
    const int* __restrict__ csrS, const float* __restrict__ w2,
    float* __restrict__ pout, int n) {
  int node = (blockIdx.x * 256 + threadIdx.x) >> 6;
  if (node >= n) return;
  int lane = threadIdx.x & 63;
  int sub = lane >> 4, l16 = lane & 15;
  int beg = rowptr[node], end = rowptr[node + 1];
  if (beg >= end) return;
  float bvals[8];
  unpack8(B4[(size_t)node * 16 + l16], bvals);
  int c = l16 * 8;
  float4 w0 = *(const float4*)&w2[c];
  float4 w1 = *(const float4*)&w2[c + 4];
  float wv[8] = {w0.x, w0.y, w0.z, w0.w, w1.x, w1.y, w1.z, w1.w};
  const uint2* A2 = (const uint2*)A8;
  for (int i = beg + sub; i < end; i += 16) {
    int i1 = i + 4, i2 = i + 8, i3 = i + 12;
    bool h1 = i1 < end, h2 = i2 < end, h3 = i3 < end;
    int s0 = csrS[i];
    int s1 = h1 ? csrS[i1] : s0;
    int s2 = h2 ? csrS[i2] : s0;
    int s3 = h3 ? csrS[i3] : s0;
    uint2 pa0 = A2[(size_t)s0 * 16 + l16];
    uint2 pa1 = A2[(size_t)s1 * 16 + l16];
    uint2 pa2 = A2[(size_t)s2 * 16 + l16];
    uint2 pa3 = A2[(size_t)s3 * 16 + l16];
    float f[8];
    float dot0 = 0.f, dot1 = 0.f, dot2 = 0.f, dot3 = 0.f;
    unpack_fp8x4(pa0.x, f); unpack_fp8x4(pa0.y, f + 4);
    #pragma unroll
    for (int j = 0; j < 8; ++j) dot0 = fmaf(fmaxf(f[j] + bvals[j], 0.f), wv[j], dot0);
    unpack_fp8x4(pa1.x, f); unpack_fp8x4(pa1.y, f + 4);
    #pragma unroll
    for (int j = 0; j < 8; ++j) dot1 = fmaf(fmaxf(f[j] + bvals[j], 0.f), wv[j], dot1);
    unpack_fp8x4(pa2.x, f); unpack_fp8x4(pa2.y, f + 4);
    #pragma unroll
    for (int j = 0; j < 8; ++j) dot2 = fmaf(fmaxf(f[j] + bvals[j], 0.f), wv[j], dot2);
    unpack_fp8x4(pa3.x, f); unpack_fp8x4(pa3.y, f + 4);
    #pragma unroll
    for (int j = 0; j < 8; ++j) dot3 = fmaf(fmaxf(f[j] + bvals[j], 0.f), wv[j], dot3);
    #pragma unroll
    for (int o = 1; o <= 8; o <<= 1) {
      dot0 += __shfl_xor(dot0, o);
      dot1 += __shfl_xor(dot1, o);
      dot2 += __shfl_xor(dot2, o);
      dot3 += __shfl_xor(dot3, o);
    }
    if (l16 == 0) {
      pout[i] = dot0;
      if (h1) pout[i1] = dot1;
      if (h2) pout[i2] = dot2;
      if (h3) pout[i3] = dot3;
    }
  }
}

// --- finalize: out[i] = sigmoid(pout[rowptr[dst[i]] + pintra[i]] + b2) ---
__global__ __launch_bounds__(256) void edge_fin_k(const float* __restrict__ pout,
    const int* __restrict__ dst, const int* __restrict__ pintra,
    const int* __restrict__ rowptr, const float* __restrict__ b2,
    float* __restrict__ out, int E) {
  int t = blockIdx.x * 256 + threadIdx.x;
  if (t >= E) return;
  int p = rowptr[dst[t]] + pintra[t];
  float z = pout[p] + b2[0];
  out[t] = 1.f / (1.f + expf(-z));
}

extern "C" void kernel_launch(void* const* d_in, const int* in_sizes, int n_in,
                              void* d_out, int out_size, void* d_ws, size_t ws_size,
                              hipStream_t stream) {
  const float* x    = (const float*)d_in[0];
  const int*   ei   = (const int*)d_in[1];
  const float* W1   = (const float*)d_in[2];
  const float* b1   = (const float*)d_in[3];
  const float* g1   = (const float*)d_in[4];
  const float* be1  = (const float*)d_in[5];
  const float* m1   = (const float*)d_in[6];
  const float* v1   = (const float*)d_in[7];
  const float* W2   = (const float*)d_in[8];
  const float* b2   = (const float*)d_in[9];
  const float* g2   = (const float*)d_in[10];
  const float* be2  = (const float*)d_in[11];
  const float* m2   = (const float*)d_in[12];
  const float* v2   = (const float*)d_in[13];
  const float* epW1 = (const float*)d_in[14];
  const float* epb1 = (const float*)d_in[15];
  const float* epW2 = (const float*)d_in[16];
  const float* epb2 = (const float*)d_in[17];

  int N = in_sizes[0] / 128;
  int E = in_sizes[1] / 2;
  const int* src = ei;
  const int* dst = ei + E;

  char* w = (char*)d_ws;
  size_t off = 0;
  auto carve = [&](size_t bytes) {
    void* p = w + off;
    off = (off + bytes + 255) & ~(size_t)255;
    return p;
  };
  u8*  bufX8 = (u8*)carve((size_t)N * 128);       // XW' fp8 (layer1/layer2 gathers)
  u16* bufH  = (u16*)carve((size_t)N * 128 * 2);  // h1 -> h2 (bf16)
  u16* bufB  = (u16*)carve((size_t)N * 128 * 2);  // B (bf16)
  u8*  bufA8 = (u8*)carve((size_t)N * 128);       // A (fp8 e4m3)
  int*   cnt   = (int*)carve((size_t)N * 4);
  int*   pintra= (int*)carve((size_t)E * 4);
  int*   rowptr= (int*)carve((size_t)(N + 1) * 4);
  float* dinv  = (float*)carve((size_t)N * 4);
  int*   csrS  = (int*)carve((size_t)E * 4);
  int*   bsum  = (int*)carve((size_t)1024 * 4);
  u16*   wsT   = (u16*)carve((size_t)4 * 16384 * 2);
  float* pout  = (float*)carve((size_t)E * 4);
  float* bnab  = (float*)carve((size_t)512 * 4);  // folded BN alpha/beta x2 layers
  (void)ws_size; (void)n_in; (void)out_size;

  int nb = (N + 255) / 256;
  int T = (E + 3) / 4;
  int tb = (T + 255) / 256;

  clear_k<<<nb, 256, 0, stream>>>(cnt, N);
  prep_k<<<257, 256, 0, stream>>>(W1, W2, epW1, b1, g1, be1, m1, v1,
                                  b2, g2, be2, m2, v2, wsT, bnab);
  count_pos_k<<<tb, 256, 0, stream>>>(dst, cnt, pintra, T, E);
  blocksum_k<<<nb, 256, 0, stream>>>(cnt, bsum, N);
  scan_bsum_k<<<1, 1024, 0, stream>>>(bsum, nb);
  scan_final_k<<<nb, 256, 0, stream>>>(cnt, bsum, rowptr, dinv, N);
  fill_csr_k<<<tb, 256, 0, stream>>>(src, dst, rowptr, pintra, csrS, T, E);

  int gb = (N + 63) / 64;
  int an = (N + 15) / 16;   // agg: 16 nodes per block (16 lanes/node)
  int ab = (N + 3) / 4;     // edge pass: wave per node
  const u16* WtW1 = wsT;
  const u16* WtW2 = wsT + 16384;
  const u16* WtA  = wsT + 2 * 16384;
  const u16* WtB  = wsT + 3 * 16384;

  // layer 1: XW' = dinv * (x @ W1) -> fp8
  gemm_mfma_k<false, true, true><<<gb, 256, 0, stream>>>(x, WtW1, dinv, bufX8, N);
  agg_bn_relu_k<<<an, 256, 0, stream>>>(bufX8, rowptr, csrS, dinv, bnab,
                                        (uint4*)bufH, N);
  // layer 2
  gemm_mfma_k<true, true, true><<<gb, 256, 0, stream>>>(bufH, WtW2, dinv, bufX8, N);
  agg_bn_relu_k<<<an, 256, 0, stream>>>(bufX8, rowptr, csrS, dinv, bnab + 256,
                                        (uint4*)bufH, N);
  // edge predictor: A (fp8, +epb1) and B (bf16), fused
  gemm_mfma2_k<<<gb, 256, 0, stream>>>(bufH, WtA, WtB, epb1, bufA8, bufB, N);
  // edge MLP partial dots (coalesced writes), then finalize with sigmoid
  edge_pass_k<<<ab, 256, 0, stream>>>(bufA8, (const uint4*)bufB, rowptr, csrS,
                                      epW2, pout, N);
  edge_fin_k<<<(E + 255) / 256, 256, 0, stream>>>(pout, dst, pintra, rowptr,
                                                  epb2, (float*)d_out, E);
}